// Round 1
// baseline (2363.323 us; speedup 1.0000x reference)
//
#include <hip/hip_runtime.h>

#define NN 100000
#define NE 1600000

// ---------------- scatter: agg[dst] += x[src], 32 channels, 8 thr/edge ----------------
__global__ __launch_bounds__(256) void scatter32(const float* __restrict__ x,
                                                 const int* __restrict__ ei,
                                                 float* __restrict__ agg) {
    int tid = blockIdx.x * 256 + threadIdx.x;
    int e = tid >> 3;          // edge
    int q = tid & 7;           // float4 quarter (8 * 4 = 32 ch)
    int src = ei[e];
    int dst = ei[NE + e];
    const float4 v = *reinterpret_cast<const float4*>(x + (size_t)src * 32 + q * 4);
    float* d = agg + (size_t)dst * 32 + q * 4;
    atomicAdd(d + 0, v.x);
    atomicAdd(d + 1, v.y);
    atomicAdd(d + 2, v.z);
    atomicAdd(d + 3, v.w);
}

// ---------------- scatter: agg[dst] += h[src], 64 channels, 16 thr/edge ----------------
__global__ __launch_bounds__(256) void scatter64(const float* __restrict__ h,
                                                 const int* __restrict__ ei,
                                                 float* __restrict__ agg) {
    int tid = blockIdx.x * 256 + threadIdx.x;
    int e = tid >> 4;
    int q = tid & 15;          // 16 * 4 = 64 ch
    int src = ei[e];
    int dst = ei[NE + e];
    const float4 v = *reinterpret_cast<const float4*>(h + (size_t)src * 64 + q * 4);
    float* d = agg + (size_t)dst * 64 + q * 4;
    atomicAdd(d + 0, v.x);
    atomicAdd(d + 1, v.y);
    atomicAdd(d + 2, v.z);
    atomicAdd(d + 3, v.w);
}

// ---------------- MLP1: h = relu( relu((agg+x)@W1 + b1) @ W2 + b2 ), 32->64->64 -------
// one wave per node; lane = output channel; inputs broadcast via shfl; weights in LDS.
__global__ __launch_bounds__(256) void mlp1(const float* __restrict__ x,
                                            const float* __restrict__ agg,
                                            const float* __restrict__ W1,
                                            const float* __restrict__ b1,
                                            const float* __restrict__ W2,
                                            const float* __restrict__ b2,
                                            float* __restrict__ h) {
    __shared__ float W1s[32 * 64];
    __shared__ float W2s[64 * 64];
    __shared__ float b1s[64];
    __shared__ float b2s[64];
    for (int i = threadIdx.x; i < 32 * 64; i += 256) W1s[i] = W1[i];
    for (int i = threadIdx.x; i < 64 * 64; i += 256) W2s[i] = W2[i];
    if (threadIdx.x < 64) {
        b1s[threadIdx.x] = b1[threadIdx.x];
        b2s[threadIdx.x] = b2[threadIdx.x];
    }
    __syncthreads();

    int lane = threadIdx.x & 63;
    int widx = threadIdx.x >> 6;
    int node = blockIdx.x * 4 + widx;   // NN = 25000*4, exact

    float aval = 0.f;
    if (lane < 32) {
        size_t off = (size_t)node * 32 + lane;
        aval = x[off] + agg[off];
    }
    float s = b1s[lane];
#pragma unroll
    for (int i = 0; i < 32; ++i) {
        float ai = __shfl(aval, i);
        s += ai * W1s[i * 64 + lane];
    }
    float t = fmaxf(s, 0.f);

    float s2 = b2s[lane];
#pragma unroll
    for (int j = 0; j < 64; ++j) {
        float tj = __shfl(t, j);
        s2 += tj * W2s[j * 64 + lane];
    }
    h[(size_t)node * 64 + lane] = fmaxf(s2, 0.f);  // outer relu of layer 1
}

// ---------------- MLP2: out = relu((agg+h)@W3 + b3) @ W4 + b4, 64->64->32 -------------
__global__ __launch_bounds__(256) void mlp2(const float* __restrict__ h,
                                            const float* __restrict__ agg,
                                            const float* __restrict__ W3,
                                            const float* __restrict__ b3,
                                            const float* __restrict__ W4,
                                            const float* __restrict__ b4,
                                            float* __restrict__ out) {
    __shared__ float W3s[64 * 64];
    __shared__ float W4s[64 * 32];
    __shared__ float b3s[64];
    __shared__ float b4s[32];
    for (int i = threadIdx.x; i < 64 * 64; i += 256) W3s[i] = W3[i];
    for (int i = threadIdx.x; i < 64 * 32; i += 256) W4s[i] = W4[i];
    if (threadIdx.x < 64) b3s[threadIdx.x] = b3[threadIdx.x];
    if (threadIdx.x < 32) b4s[threadIdx.x] = b4[threadIdx.x];
    __syncthreads();

    int lane = threadIdx.x & 63;
    int widx = threadIdx.x >> 6;
    int node = blockIdx.x * 4 + widx;

    size_t off = (size_t)node * 64 + lane;
    float aval = h[off] + agg[off];

    float s = b3s[lane];
#pragma unroll
    for (int i = 0; i < 64; ++i) {
        float ai = __shfl(aval, i);
        s += ai * W3s[i * 64 + lane];
    }
    float t = fmaxf(s, 0.f);

    float s2 = b4s[lane & 31];
#pragma unroll
    for (int j = 0; j < 64; ++j) {
        float tj = __shfl(t, j);
        s2 += tj * W4s[j * 32 + (lane & 31)];
    }
    if (lane < 32) out[(size_t)node * 32 + lane] = s2;   // no final relu
}

extern "C" void kernel_launch(void* const* d_in, const int* in_sizes, int n_in,
                              void* d_out, int out_size, void* d_ws, size_t ws_size,
                              hipStream_t stream) {
    const float* x  = (const float*)d_in[0];
    const int*   ei = (const int*)d_in[1];
    const float* W1 = (const float*)d_in[2];
    const float* b1 = (const float*)d_in[3];
    const float* W2 = (const float*)d_in[4];
    const float* b2 = (const float*)d_in[5];
    const float* W3 = (const float*)d_in[6];
    const float* b3 = (const float*)d_in[7];
    const float* W4 = (const float*)d_in[8];
    const float* b4 = (const float*)d_in[9];
    float* out = (float*)d_out;

    char* ws = (char*)d_ws;
    float* h   = (float*)ws;                                  // N*64 f32 = 25.6 MB
    float* agg = (float*)(ws + (size_t)NN * 64 * 4);          // N*64 f32, reused (agg1 uses first N*32)

    // ---- layer 1 ----
    hipMemsetAsync(agg, 0, (size_t)NN * 32 * 4, stream);
    scatter32<<<(NE * 8) / 256, 256, 0, stream>>>(x, ei, agg);
    mlp1<<<NN / 4, 256, 0, stream>>>(x, agg, W1, b1, W2, b2, h);

    // ---- layer 2 ----
    hipMemsetAsync(agg, 0, (size_t)NN * 64 * 4, stream);
    scatter64<<<(NE * 16) / 256, 256, 0, stream>>>(h, ei, agg);
    mlp2<<<NN / 4, 256, 0, stream>>>(h, agg, W3, b3, W4, b4, out);
}

// Round 2
// 999.429 us; speedup vs baseline: 2.3647x; 2.3647x over previous
//
#include <hip/hip_runtime.h>

#define NN 100000
#define NE 1600000
#define NB 391   // ceil(NN/256)

// ============================ CSR build ============================

__global__ __launch_bounds__(256) void hist_k(const int* __restrict__ ei,
                                              int* __restrict__ deg) {
    int e = blockIdx.x * 256 + threadIdx.x;
    atomicAdd(&deg[ei[NE + e]], 1);
}

// inclusive scan of 256-elem chunks; block sums out
__global__ __launch_bounds__(256) void scan1_k(const int* __restrict__ deg,
                                               int* __restrict__ scanned,
                                               int* __restrict__ bsums) {
    __shared__ int tmp[256];
    int i = blockIdx.x * 256 + threadIdx.x;
    int v = (i < NN) ? deg[i] : 0;
    tmp[threadIdx.x] = v;
    __syncthreads();
#pragma unroll
    for (int off = 1; off < 256; off <<= 1) {
        int t = (threadIdx.x >= off) ? tmp[threadIdx.x - off] : 0;
        __syncthreads();
        tmp[threadIdx.x] += t;
        __syncthreads();
    }
    if (i < NN) scanned[i] = tmp[threadIdx.x];
    if (threadIdx.x == 255) bsums[blockIdx.x] = tmp[255];
}

// inclusive scan of the NB block sums (NB < 512)
__global__ __launch_bounds__(512) void scan2_k(int* __restrict__ bsums) {
    __shared__ int tmp[512];
    int v = (threadIdx.x < NB) ? bsums[threadIdx.x] : 0;
    tmp[threadIdx.x] = v;
    __syncthreads();
#pragma unroll
    for (int off = 1; off < 512; off <<= 1) {
        int t = (threadIdx.x >= off) ? tmp[threadIdx.x - off] : 0;
        __syncthreads();
        tmp[threadIdx.x] += t;
        __syncthreads();
    }
    if (threadIdx.x < NB) bsums[threadIdx.x] = tmp[threadIdx.x];
}

// finalize: rowptr (exclusive starts, +total at [NN]) and cursor copy
__global__ __launch_bounds__(256) void scan3_k(const int* __restrict__ scanned,
                                               const int* __restrict__ bsums,
                                               const int* __restrict__ deg,
                                               int* __restrict__ rowptr,
                                               int* __restrict__ cursor) {
    int i = blockIdx.x * 256 + threadIdx.x;
    if (i < NN) {
        int incl = scanned[i] + (blockIdx.x ? bsums[blockIdx.x - 1] : 0);
        rowptr[i + 1] = incl;
        cursor[i] = incl - deg[i];
        if (i == 0) rowptr[0] = 0;
    }
}

__global__ __launch_bounds__(256) void fill_k(const int* __restrict__ ei,
                                              int* __restrict__ cursor,
                                              int* __restrict__ col) {
    int e = blockIdx.x * 256 + threadIdx.x;
    int dst = ei[NE + e];
    int pos = atomicAdd(&cursor[dst], 1);
    col[pos] = ei[e];
}

// ============ layer 1: gather(x) + relu(relu((agg+x)W1+b1)W2+b2) ============
// one wave per node (grid-stride); lanes 0-31 / 32-63 each take every other edge.
__global__ __launch_bounds__(256) void fused1(const float* __restrict__ x,
                                              const int* __restrict__ rowptr,
                                              const int* __restrict__ col,
                                              const float* __restrict__ W1,
                                              const float* __restrict__ b1,
                                              const float* __restrict__ W2,
                                              const float* __restrict__ b2,
                                              float* __restrict__ h) {
    __shared__ float W1s[32 * 64];
    __shared__ float W2s[64 * 64];
    __shared__ float b1s[64];
    __shared__ float b2s[64];
    for (int i = threadIdx.x; i < 32 * 64; i += 256) W1s[i] = W1[i];
    for (int i = threadIdx.x; i < 64 * 64; i += 256) W2s[i] = W2[i];
    if (threadIdx.x < 64) {
        b1s[threadIdx.x] = b1[threadIdx.x];
        b2s[threadIdx.x] = b2[threadIdx.x];
    }
    __syncthreads();

    int lane = threadIdx.x & 63;
    int c = lane & 31;          // channel
    int p = lane >> 5;          // edge parity
    int gw = blockIdx.x * 4 + (threadIdx.x >> 6);
    int nwaves = gridDim.x * 4;

    for (int node = gw; node < NN; node += nwaves) {
        int s0 = rowptr[node], s1 = rowptr[node + 1];
        float acc = 0.f;
        for (int e = s0 + p; e < s1; e += 2)
            acc += x[(size_t)col[e] * 32 + c];
        acc += __shfl_xor(acc, 32);                 // combine both halves
        float aval = acc + x[(size_t)node * 32 + c];

        float s = b1s[lane];
#pragma unroll
        for (int i = 0; i < 32; ++i)
            s += __shfl(aval, i) * W1s[i * 64 + lane];
        float t = fmaxf(s, 0.f);

        float s2 = b2s[lane];
#pragma unroll
        for (int j = 0; j < 64; ++j)
            s2 += __shfl(t, j) * W2s[j * 64 + lane];
        h[(size_t)node * 64 + lane] = fmaxf(s2, 0.f);
    }
}

// ============ layer 2: gather(h) + relu((agg+h)W3+b3)W4+b4 ============
__global__ __launch_bounds__(256) void fused2(const float* __restrict__ h,
                                              const int* __restrict__ rowptr,
                                              const int* __restrict__ col,
                                              const float* __restrict__ W3,
                                              const float* __restrict__ b3,
                                              const float* __restrict__ W4,
                                              const float* __restrict__ b4,
                                              float* __restrict__ out) {
    __shared__ float W3s[64 * 64];
    __shared__ float W4s[64 * 32];
    __shared__ float b3s[64];
    __shared__ float b4s[32];
    for (int i = threadIdx.x; i < 64 * 64; i += 256) W3s[i] = W3[i];
    for (int i = threadIdx.x; i < 64 * 32; i += 256) W4s[i] = W4[i];
    if (threadIdx.x < 64) b3s[threadIdx.x] = b3[threadIdx.x];
    if (threadIdx.x < 32) b4s[threadIdx.x] = b4[threadIdx.x];
    __syncthreads();

    int lane = threadIdx.x & 63;
    int gw = blockIdx.x * 4 + (threadIdx.x >> 6);
    int nwaves = gridDim.x * 4;

    for (int node = gw; node < NN; node += nwaves) {
        int s0 = rowptr[node], s1 = rowptr[node + 1];
        float acc = 0.f;
        for (int e = s0; e < s1; ++e)
            acc += h[(size_t)col[e] * 64 + lane];
        float aval = acc + h[(size_t)node * 64 + lane];

        float s = b3s[lane];
#pragma unroll
        for (int i = 0; i < 64; ++i)
            s += __shfl(aval, i) * W3s[i * 64 + lane];
        float t = fmaxf(s, 0.f);

        float s2 = b4s[lane & 31];
#pragma unroll
        for (int j = 0; j < 64; ++j)
            s2 += __shfl(t, j) * W4s[j * 32 + (lane & 31)];
        if (lane < 32) out[(size_t)node * 32 + lane] = s2;
    }
}

extern "C" void kernel_launch(void* const* d_in, const int* in_sizes, int n_in,
                              void* d_out, int out_size, void* d_ws, size_t ws_size,
                              hipStream_t stream) {
    const float* x  = (const float*)d_in[0];
    const int*   ei = (const int*)d_in[1];
    const float* W1 = (const float*)d_in[2];
    const float* b1 = (const float*)d_in[3];
    const float* W2 = (const float*)d_in[4];
    const float* b2 = (const float*)d_in[5];
    const float* W3 = (const float*)d_in[6];
    const float* b3 = (const float*)d_in[7];
    const float* W4 = (const float*)d_in[8];
    const float* b4 = (const float*)d_in[9];
    float* out = (float*)d_out;

    char* ws = (char*)d_ws;
    float* h      = (float*)ws;                                   ws += (size_t)NN * 64 * 4;  // 25.6 MB
    int*   col    = (int*)ws;                                     ws += (size_t)NE * 4;       // 6.4 MB
    int*   deg    = (int*)ws;                                     ws += (size_t)NN * 4;
    int*   scanned= (int*)ws;                                     ws += (size_t)NN * 4;
    int*   rowptr = (int*)ws;                                     ws += (size_t)(NN + 1) * 4;
    int*   cursor = (int*)ws;                                     ws += (size_t)NN * 4;
    int*   bsums  = (int*)ws;                                     ws += (size_t)NB * 4;

    // ---- CSR build ----
    hipMemsetAsync(deg, 0, (size_t)NN * 4, stream);
    hist_k<<<NE / 256, 256, 0, stream>>>(ei, deg);
    scan1_k<<<NB, 256, 0, stream>>>(deg, scanned, bsums);
    scan2_k<<<1, 512, 0, stream>>>(bsums);
    scan3_k<<<NB, 256, 0, stream>>>(scanned, bsums, deg, rowptr, cursor);
    fill_k<<<NE / 256, 256, 0, stream>>>(ei, cursor, col);

    // ---- fused layers ----
    fused1<<<1536, 256, 0, stream>>>(x, rowptr, col, W1, b1, W2, b2, h);
    fused2<<<1536, 256, 0, stream>>>(h, rowptr, col, W3, b3, W4, b4, out);
}

// Round 3
// 859.882 us; speedup vs baseline: 2.7484x; 1.1623x over previous
//
#include <hip/hip_runtime.h>

#define NN 100000
#define NE 1600000
#define NB 391   // ceil(NN/256)

// ============================ CSR build ============================

__global__ __launch_bounds__(256) void hist_k(const int* __restrict__ ei,
                                              int* __restrict__ deg) {
    int e = blockIdx.x * 256 + threadIdx.x;
    atomicAdd(&deg[ei[NE + e]], 1);
}

__global__ __launch_bounds__(256) void scan1_k(const int* __restrict__ deg,
                                               int* __restrict__ scanned,
                                               int* __restrict__ bsums) {
    __shared__ int tmp[256];
    int i = blockIdx.x * 256 + threadIdx.x;
    int v = (i < NN) ? deg[i] : 0;
    tmp[threadIdx.x] = v;
    __syncthreads();
#pragma unroll
    for (int off = 1; off < 256; off <<= 1) {
        int t = (threadIdx.x >= off) ? tmp[threadIdx.x - off] : 0;
        __syncthreads();
        tmp[threadIdx.x] += t;
        __syncthreads();
    }
    if (i < NN) scanned[i] = tmp[threadIdx.x];
    if (threadIdx.x == 255) bsums[blockIdx.x] = tmp[255];
}

__global__ __launch_bounds__(512) void scan2_k(int* __restrict__ bsums) {
    __shared__ int tmp[512];
    int v = (threadIdx.x < NB) ? bsums[threadIdx.x] : 0;
    tmp[threadIdx.x] = v;
    __syncthreads();
#pragma unroll
    for (int off = 1; off < 512; off <<= 1) {
        int t = (threadIdx.x >= off) ? tmp[threadIdx.x - off] : 0;
        __syncthreads();
        tmp[threadIdx.x] += t;
        __syncthreads();
    }
    if (threadIdx.x < NB) bsums[threadIdx.x] = tmp[threadIdx.x];
}

__global__ __launch_bounds__(256) void scan3_k(const int* __restrict__ scanned,
                                               const int* __restrict__ bsums,
                                               const int* __restrict__ deg,
                                               int* __restrict__ rowptr,
                                               int* __restrict__ cursor) {
    int i = blockIdx.x * 256 + threadIdx.x;
    if (i < NN) {
        int incl = scanned[i] + (blockIdx.x ? bsums[blockIdx.x - 1] : 0);
        rowptr[i + 1] = incl;
        cursor[i] = incl - deg[i];
        if (i == 0) rowptr[0] = 0;
    }
}

__global__ __launch_bounds__(256) void fill_k(const int* __restrict__ ei,
                                              int* __restrict__ cursor,
                                              int* __restrict__ col) {
    int e = blockIdx.x * 256 + threadIdx.x;
    int dst = ei[NE + e];
    int pos = atomicAdd(&cursor[dst], 1);
    col[pos] = ei[e];
}

// ============ layer 1: gather(x) + relu(relu((agg+x)W1+b1)W2+b2) ============
// one wave per node; lanes 0-31 / 32-63 take alternate edges; 4-way ILP unroll.
__global__ __launch_bounds__(256, 4) void fused1(const float* __restrict__ x,
                                                 const int* __restrict__ rowptr,
                                                 const int* __restrict__ col,
                                                 const float* __restrict__ W1,
                                                 const float* __restrict__ b1,
                                                 const float* __restrict__ W2,
                                                 const float* __restrict__ b2,
                                                 float* __restrict__ h) {
    __shared__ float W1s[32 * 64];
    __shared__ float W2s[64 * 64];
    __shared__ float b1s[64];
    __shared__ float b2s[64];
    for (int i = threadIdx.x; i < 32 * 64; i += 256) W1s[i] = W1[i];
    for (int i = threadIdx.x; i < 64 * 64; i += 256) W2s[i] = W2[i];
    if (threadIdx.x < 64) {
        b1s[threadIdx.x] = b1[threadIdx.x];
        b2s[threadIdx.x] = b2[threadIdx.x];
    }
    __syncthreads();

    int lane = threadIdx.x & 63;
    int c = lane & 31;          // channel
    int p = lane >> 5;          // edge parity
    int gw = blockIdx.x * 4 + (threadIdx.x >> 6);
    int nwaves = gridDim.x * 4;

    for (int node = gw; node < NN; node += nwaves) {
        int s0 = rowptr[node], s1 = rowptr[node + 1];
        float self = x[(size_t)node * 32 + c];   // issue early, independent

        float a0 = 0.f, a1 = 0.f, a2 = 0.f, a3 = 0.f;
        int e = s0 + p;
        for (; e + 6 < s1; e += 8) {             // this parity: e, e+2, e+4, e+6
            int c0 = col[e], c1 = col[e + 2], c2 = col[e + 4], c3 = col[e + 6];
            a0 += x[(size_t)c0 * 32 + c];
            a1 += x[(size_t)c1 * 32 + c];
            a2 += x[(size_t)c2 * 32 + c];
            a3 += x[(size_t)c3 * 32 + c];
        }
        for (; e < s1; e += 2)
            a0 += x[(size_t)col[e] * 32 + c];
        float acc = (a0 + a1) + (a2 + a3);
        acc += __shfl_xor(acc, 32);              // combine parity halves
        float aval = acc + self;

        float s = b1s[lane];
#pragma unroll
        for (int i = 0; i < 32; ++i)
            s += __shfl(aval, i) * W1s[i * 64 + lane];
        float t = fmaxf(s, 0.f);

        float s2 = b2s[lane];
#pragma unroll
        for (int j = 0; j < 64; ++j)
            s2 += __shfl(t, j) * W2s[j * 64 + lane];
        h[(size_t)node * 64 + lane] = fmaxf(s2, 0.f);
    }
}

// ============ layer 2: gather(h) + relu((agg+h)W3+b3)W4+b4 ============
__global__ __launch_bounds__(256, 4) void fused2(const float* __restrict__ h,
                                                 const int* __restrict__ rowptr,
                                                 const int* __restrict__ col,
                                                 const float* __restrict__ W3,
                                                 const float* __restrict__ b3,
                                                 const float* __restrict__ W4,
                                                 const float* __restrict__ b4,
                                                 float* __restrict__ out) {
    __shared__ float W3s[64 * 64];
    __shared__ float W4s[64 * 32];
    __shared__ float b3s[64];
    __shared__ float b4s[32];
    for (int i = threadIdx.x; i < 64 * 64; i += 256) W3s[i] = W3[i];
    for (int i = threadIdx.x; i < 64 * 32; i += 256) W4s[i] = W4[i];
    if (threadIdx.x < 64) b3s[threadIdx.x] = b3[threadIdx.x];
    if (threadIdx.x < 32) b4s[threadIdx.x] = b4[threadIdx.x];
    __syncthreads();

    int lane = threadIdx.x & 63;
    int gw = blockIdx.x * 4 + (threadIdx.x >> 6);
    int nwaves = gridDim.x * 4;

    for (int node = gw; node < NN; node += nwaves) {
        int s0 = rowptr[node], s1 = rowptr[node + 1];
        float self = h[(size_t)node * 64 + lane];

        float a0 = 0.f, a1 = 0.f, a2 = 0.f, a3 = 0.f;
        int e = s0;
        for (; e + 3 < s1; e += 4) {
            int c0 = col[e], c1 = col[e + 1], c2 = col[e + 2], c3 = col[e + 3];
            a0 += h[(size_t)c0 * 64 + lane];
            a1 += h[(size_t)c1 * 64 + lane];
            a2 += h[(size_t)c2 * 64 + lane];
            a3 += h[(size_t)c3 * 64 + lane];
        }
        for (; e < s1; ++e)
            a0 += h[(size_t)col[e] * 64 + lane];
        float aval = ((a0 + a1) + (a2 + a3)) + self;

        float s = b3s[lane];
#pragma unroll
        for (int i = 0; i < 64; ++i)
            s += __shfl(aval, i) * W3s[i * 64 + lane];
        float t = fmaxf(s, 0.f);

        float s2 = b4s[lane & 31];
#pragma unroll
        for (int j = 0; j < 64; ++j)
            s2 += __shfl(t, j) * W4s[j * 32 + (lane & 31)];
        if (lane < 32) out[(size_t)node * 32 + lane] = s2;
    }
}

extern "C" void kernel_launch(void* const* d_in, const int* in_sizes, int n_in,
                              void* d_out, int out_size, void* d_ws, size_t ws_size,
                              hipStream_t stream) {
    const float* x  = (const float*)d_in[0];
    const int*   ei = (const int*)d_in[1];
    const float* W1 = (const float*)d_in[2];
    const float* b1 = (const float*)d_in[3];
    const float* W2 = (const float*)d_in[4];
    const float* b2 = (const float*)d_in[5];
    const float* W3 = (const float*)d_in[6];
    const float* b3 = (const float*)d_in[7];
    const float* W4 = (const float*)d_in[8];
    const float* b4 = (const float*)d_in[9];
    float* out = (float*)d_out;

    char* ws = (char*)d_ws;
    float* h      = (float*)ws;                                   ws += (size_t)NN * 64 * 4;  // 25.6 MB
    int*   col    = (int*)ws;                                     ws += (size_t)NE * 4;       // 6.4 MB
    int*   deg    = (int*)ws;                                     ws += (size_t)NN * 4;
    int*   scanned= (int*)ws;                                     ws += (size_t)NN * 4;
    int*   rowptr = (int*)ws;                                     ws += (size_t)(NN + 1) * 4;
    int*   cursor = (int*)ws;                                     ws += (size_t)NN * 4;
    int*   bsums  = (int*)ws;                                     ws += (size_t)NB * 4;

    // ---- CSR build ----
    hipMemsetAsync(deg, 0, (size_t)NN * 4, stream);
    hist_k<<<NE / 256, 256, 0, stream>>>(ei, deg);
    scan1_k<<<NB, 256, 0, stream>>>(deg, scanned, bsums);
    scan2_k<<<1, 512, 0, stream>>>(bsums);
    scan3_k<<<NB, 256, 0, stream>>>(scanned, bsums, deg, rowptr, cursor);
    fill_k<<<NE / 256, 256, 0, stream>>>(ei, cursor, col);

    // ---- fused layers ----
    fused1<<<1024, 256, 0, stream>>>(x, rowptr, col, W1, b1, W2, b2, h);
    fused2<<<1024, 256, 0, stream>>>(h, rowptr, col, W3, b3, W4, b4, out);
}